// Round 3
// baseline (335.295 us; speedup 1.0000x reference)
//
#include <hip/hip_runtime.h>
#include <cstdint>
#include <cstddef>

#define DIM    256
#define NE     2048
#define NROWS  65536

// d_out flat fp32 layout: quantize_st | diff | embed_ind | perplexity
#define OFF_DIFF ((size_t)16777216)
#define OFF_IND  ((size_t)16777217)
#define OFF_PERP ((size_t)16842753)

// d_ws byte layout
#define WS_DIFF   0                      // double
#define WS_CNT    64                     // int[2048]
#define WS_EN     8256                   // float[2048]  ||e||^2
#define WS_ENC    16448                  // float[2048]  (128 - ||e||^2/2)*2048
#define WS_ET     24640                  // float[2048*256] embedT
#define WS_BPK    2121792                // _Float16 packed B: [64 nc][hi 16KB | lo 16KB]
#define WS_NEED_V2 ((size_t)(2121792 + 2097152))

typedef __attribute__((ext_vector_type(8)))  _Float16 half8;
typedef __attribute__((ext_vector_type(16))) float    float16v;

__device__ __forceinline__ float16v mfma32(half8 a, half8 b, float16v c) {
    return __builtin_amdgcn_mfma_f32_32x32x16_f16(a, b, c, 0, 0, 0);
}

__device__ __forceinline__ void gld16(const void* g, void* l) {
    __builtin_amdgcn_global_load_lds((const __attribute__((address_space(1))) void*)g,
                                     (__attribute__((address_space(3))) void*)l,
                                     16, 0, 0);
}

// ---------------- prep kernels ----------------

// ||e_j||^2 (double accumulate) + pre-scaled packed-score constant
__global__ __launch_bounds__(256) void k_prep(const float* __restrict__ embed,
                                              float* __restrict__ enorm,
                                              float* __restrict__ enc) {
    int j = blockIdx.x * 256 + threadIdx.x;
    double s = 0.0;
    for (int d = 0; d < DIM; ++d) {
        float e = embed[(size_t)d * NE + j];
        s += (double)e * (double)e;
    }
    float en = (float)s;
    enorm[j] = en;
    enc[j]   = (128.0f - 0.5f * en) * 2048.0f;
}

// pack embed into 32x32x16 B-fragment order (hi|lo per 32-col chunk) + embedT
// fragment-lane tt: nc = tt>>10, tfrag = (tt>>6)&15, lane = tt&63
// lane holds B[k = tfrag*16 + (lane>>5)*8 + j][col = nc*32 + (lane&31)], j=0..7
__global__ __launch_bounds__(256) void k_pack(const float* __restrict__ embed,
                                              _Float16* __restrict__ bpk,
                                              float* __restrict__ embedT) {
    int tt    = blockIdx.x * 256 + threadIdx.x;   // 0..65535
    int nc    = tt >> 10;
    int tfrag = (tt >> 6) & 15;
    int lane  = tt & 63;
    int col   = nc * 32 + (lane & 31);
    int k0    = tfrag * 16 + (lane >> 5) * 8;
    half8 h, l;
#pragma unroll
    for (int j = 0; j < 8; ++j) {
        float e = embed[(size_t)(k0 + j) * NE + col];
        _Float16 eh = (_Float16)e;
        h[j] = eh;
        l[j] = (_Float16)(e - (float)eh);
        embedT[(size_t)col * DIM + k0 + j] = e;
    }
    char* base = (char*)bpk + (size_t)nc * 32768 + (size_t)tfrag * 1024 + (size_t)lane * 16;
    *(half8*)(base)         = h;
    *(half8*)(base + 16384) = l;
}

// ---------------- main fused MFMA kernel ----------------

__global__ __launch_bounds__(256, 2) void k_gemm(
    const float* __restrict__ inp,
    const _Float16* __restrict__ bpk,
    const float* __restrict__ enorm,
    const float* __restrict__ enc,
    const float* __restrict__ embedT,
    float* __restrict__ out,
    int* __restrict__ counts,
    double* __restrict__ diffacc)
{
    __shared__ __align__(16) char ldsB[2][32768];   // per buf: hi 16KB | lo 16KB
    __shared__ float encs[NE];                      // 8 KB pre-scaled constants
    const int tid  = threadIdx.x;
    const int w    = tid >> 6;
    const int lane = tid & 63;
    const int kh   = lane >> 5;       // 0/1
    const int m    = lane & 31;       // col within chunk (C-layout), row for A
    const int mw   = blockIdx.x * 128 + w * 32;

#pragma unroll
    for (int i = 0; i < 8; ++i) encs[tid + 256 * i] = enc[tid + 256 * i];

    // ---- A: 32 rows/wave stationary, f16 hi+lo, 32x32x16 A-layout ----
    // lane holds A[row = m][k = t*16 + kh*8 + j]
    half8 ah[16], al[16];
    {
        const float* xr = inp + (size_t)(mw + m) * DIM + kh * 8;
#pragma unroll
        for (int t = 0; t < 16; ++t) {
            float4 f0 = *(const float4*)(xr + t * 16);
            float4 f1 = *(const float4*)(xr + t * 16 + 4);
            float fs[8] = {f0.x, f0.y, f0.z, f0.w, f1.x, f1.y, f1.z, f1.w};
            half8 hh, ll;
#pragma unroll
            for (int j = 0; j < 8; ++j) {
                _Float16 xh = (_Float16)fs[j];
                hh[j] = xh;
                ll[j] = (_Float16)(fs[j] - (float)xh);
            }
            ah[t] = hh;
            al[t] = ll;
        }
    }

    // packed top-2 per C-reg slot (16 rows per thread, 1 col each)
    int P1[16], P2[16];
#pragma unroll
    for (int r = 0; r < 16; ++r) { P1[r] = (int)0x80000000; P2[r] = (int)0x80000000; }

    // stage nc=0: wave w stages 8 of the 32 1KB segments
    {
        const char* src = (const char*)bpk;
#pragma unroll
        for (int s = 0; s < 8; ++s) {
            int seg = w * 8 + s;
            gld16(src + seg * 1024 + lane * 16, &ldsB[0][0] + seg * 1024);
        }
    }
    __syncthreads();

    for (int nc = 0; nc < 64; ++nc) {
        int pn = nc & 1;
        if (nc < 63) {
            const char* src = (const char*)bpk + (size_t)(nc + 1) * 32768;
            char* dst = &ldsB[pn ^ 1][0];
#pragma unroll
            for (int s = 0; s < 8; ++s) {
                int seg = w * 8 + s;
                gld16(src + seg * 1024 + lane * 16, dst + seg * 1024);
            }
        }

        float en = encs[nc * 32 + m];   // pre-scaled, per-col
        const char* bb = &ldsB[pn][0] + lane * 16;

        float16v acc = {};
#pragma unroll
        for (int t = 0; t < 16; ++t) {
            half8 bh = *(const half8*)(bb + t * 1024);
            half8 bl = *(const half8*)(bb + 16384 + t * 1024);
            acc = mfma32(ah[t], bh, acc);
            acc = mfma32(al[t], bh, acc);
            acc = mfma32(ah[t], bl, acc);
        }

        int colp = nc * 32 + m;
#pragma unroll
        for (int r = 0; r < 16; ++r) {
            float sf = fmaf(acc[r], 2048.0f, en);
            sf = __builtin_amdgcn_fmed3f(sf, -1048064.0f, 1048064.0f);
            int si = (int)sf;
            int p  = (int)(((unsigned)si << 11) | (unsigned)colp);
            int mn = (P1[r] < p) ? P1[r] : p;
            P2[r]  = (P2[r] > mn) ? P2[r] : mn;
            P1[r]  = (P1[r] > p) ? P1[r] : p;
        }
        __syncthreads();
    }

    // ---- cross-lane top-2 merge over the 32 col-lanes (same kh group) ----
#pragma unroll
    for (int r = 0; r < 16; ++r) {
        int p1 = P1[r], p2 = P2[r];
#pragma unroll
        for (int msk = 1; msk < 32; msk <<= 1) {
            int o1 = __shfl_xor(p1, msk);
            int o2 = __shfl_xor(p2, msk);
            int mx2 = (p2 > o2) ? p2 : o2;
            int mn1 = (p1 < o1) ? p1 : o1;
            p2 = (mx2 > mn1) ? mx2 : mn1;
            p1 = (p1 > o1) ? p1 : o1;
        }
        P1[r] = p1; P2[r] = p2;
    }

    // ---- epilogue: exact fp32 rescore of top-2 per row, gather, write, diff ----
    double dsum = 0.0;
#pragma unroll
    for (int rr = 0; rr < 32; ++rr) {
        const int reg = (rr & 3) | (((rr >> 3) & 3) << 2);
        const int src = ((rr >> 2) & 1) << 5;
        int i1 = __shfl(P1[reg], src) & 2047;
        int i2 = __shfl(P2[reg], src) & 2047;
        int row = mw + rr;
        float4 xv = *(const float4*)(inp    + (size_t)row * DIM + lane * 4);
        float4 e1 = *(const float4*)(embedT + (size_t)i1  * DIM + lane * 4);
        float4 e2 = *(const float4*)(embedT + (size_t)i2  * DIM + lane * 4);
        float d1 = xv.x * e1.x + xv.y * e1.y + xv.z * e1.z + xv.w * e1.w;
        float d2 = xv.x * e2.x + xv.y * e2.y + xv.z * e2.z + xv.w * e2.w;
#pragma unroll
        for (int msk = 1; msk < 64; msk <<= 1) {
            d1 += __shfl_xor(d1, msk);
            d2 += __shfl_xor(d2, msk);
        }
        float s1 = 2.f * d1 - enorm[i1];
        float s2 = 2.f * d2 - enorm[i2];
        bool take2 = (s2 > s1) || (s2 == s1 && i2 < i1);
        int win = take2 ? i2 : i1;
        float4 qv = take2 ? e2 : e1;
        *(float4*)(out + (size_t)row * DIM + lane * 4) = qv;
        float dx = qv.x - xv.x, dy = qv.y - xv.y;
        float dz = qv.z - xv.z, dw = qv.w - xv.w;
        dsum += (double)(dx * dx + dy * dy + dz * dz + dw * dw);
        if (lane == 0) {
            out[OFF_IND + row] = (float)win;
            atomicAdd(&counts[win], 1);
        }
    }
#pragma unroll
    for (int msk = 1; msk < 64; msk <<= 1) dsum += __shfl_xor(dsum, msk);
    if (lane == 0) atomicAdd(diffacc, dsum);
}

// ---------------- fallback (small ws): round-1 vector kernel ----------------
__global__ __launch_bounds__(256) void k_main(const float* __restrict__ inp,
                                              const float* __restrict__ embed,
                                              const float* __restrict__ enorm,
                                              float* __restrict__ out,
                                              int* __restrict__ counts,
                                              double* __restrict__ diffacc) {
    __shared__ float XsT[DIM][64];
    const int tid = threadIdx.x;
    const int m0  = blockIdx.x * 64;
#pragma unroll
    for (int i = 0; i < 16; ++i) {
        int f = tid + 256 * i;
        int row = f >> 6, c4 = f & 63;
        float4 v = *(const float4*)&inp[(size_t)(m0 + row) * DIM + c4 * 4];
        XsT[c4 * 4 + 0][row] = v.x; XsT[c4 * 4 + 1][row] = v.y;
        XsT[c4 * 4 + 2][row] = v.z; XsT[c4 * 4 + 3][row] = v.w;
    }
    __syncthreads();
    const int tx = tid & 15, ty = tid >> 4;
    float bv[4]; int bi[4];
#pragma unroll
    for (int mi = 0; mi < 4; ++mi) { bv[mi] = -1e30f; bi[mi] = 0x7fffffff; }
    for (int n0 = 0; n0 < NE; n0 += 64) {
        float acc[4][4] = {};
        const float* bp = embed + n0 + tx * 4;
        const float* ap = &XsT[0][ty * 4];
#pragma unroll 8
        for (int k = 0; k < DIM; ++k) {
            float4 b4 = *(const float4*)(bp + (size_t)k * NE);
            float4 a4 = *(const float4*)(ap + k * 64);
            acc[0][0] = fmaf(a4.x, b4.x, acc[0][0]); acc[0][1] = fmaf(a4.x, b4.y, acc[0][1]);
            acc[0][2] = fmaf(a4.x, b4.z, acc[0][2]); acc[0][3] = fmaf(a4.x, b4.w, acc[0][3]);
            acc[1][0] = fmaf(a4.y, b4.x, acc[1][0]); acc[1][1] = fmaf(a4.y, b4.y, acc[1][1]);
            acc[1][2] = fmaf(a4.y, b4.z, acc[1][2]); acc[1][3] = fmaf(a4.y, b4.w, acc[1][3]);
            acc[2][0] = fmaf(a4.z, b4.x, acc[2][0]); acc[2][1] = fmaf(a4.z, b4.y, acc[2][1]);
            acc[2][2] = fmaf(a4.z, b4.z, acc[2][2]); acc[2][3] = fmaf(a4.z, b4.w, acc[2][3]);
            acc[3][0] = fmaf(a4.w, b4.x, acc[3][0]); acc[3][1] = fmaf(a4.w, b4.y, acc[3][1]);
            acc[3][2] = fmaf(a4.w, b4.z, acc[3][2]); acc[3][3] = fmaf(a4.w, b4.w, acc[3][3]);
        }
        float4 en4 = *(const float4*)&enorm[n0 + tx * 4];
        int c0 = n0 + tx * 4;
#pragma unroll
        for (int mi = 0; mi < 4; ++mi) {
            float s0 = 2.f * acc[mi][0] - en4.x, s1 = 2.f * acc[mi][1] - en4.y;
            float s2 = 2.f * acc[mi][2] - en4.z, s3 = 2.f * acc[mi][3] - en4.w;
            float v = s0; int idx = c0;
            if (s1 > v) { v = s1; idx = c0 + 1; }
            if (s2 > v) { v = s2; idx = c0 + 2; }
            if (s3 > v) { v = s3; idx = c0 + 3; }
#pragma unroll
            for (int o = 1; o < 16; o <<= 1) {
                float ov = __shfl_xor(v, o, 64); int oi = __shfl_xor(idx, o, 64);
                if (ov > v || (ov == v && oi < idx)) { v = ov; idx = oi; }
            }
            if (v > bv[mi] || (v == bv[mi] && idx < bi[mi])) { bv[mi] = v; bi[mi] = idx; }
        }
    }
    __syncthreads();
    int* sidx = (int*)&XsT[0][0];
    if (tx == 0) {
#pragma unroll
        for (int mi = 0; mi < 4; ++mi) {
            int rl = ty * 4 + mi; int idx = bi[mi];
            sidx[rl] = idx;
            out[OFF_IND + m0 + rl] = (float)idx;
            atomicAdd(&counts[idx], 1);
        }
    }
    __syncthreads();
    float dsum = 0.f;
    for (int rl = 0; rl < 64; ++rl) {
        int idx = sidx[rl];
        float qv = embed[(size_t)tid * NE + idx];
        float x = inp[(size_t)(m0 + rl) * DIM + tid];
        out[(size_t)(m0 + rl) * DIM + tid] = qv;
        float d = qv - x;
        dsum = fmaf(d, d, dsum);
    }
    double ds = (double)dsum;
#pragma unroll
    for (int o = 32; o > 0; o >>= 1) ds += __shfl_down(ds, o, 64);
    double* red = (double*)&XsT[4][0];
    if ((tid & 63) == 0) red[tid >> 6] = ds;
    __syncthreads();
    if (tid == 0) atomicAdd(diffacc, red[0] + red[1] + red[2] + red[3]);
}

// ---------------- finalize ----------------
__global__ __launch_bounds__(256) void k_fin(const int* __restrict__ counts,
                                             const double* __restrict__ diffacc,
                                             float* __restrict__ out) {
    __shared__ double red[4];
    int tid = threadIdx.x;
    double s = 0.0;
    for (int i = tid; i < NE; i += 256) {
        int c = counts[i];
        if (c > 0) {
            float p = (float)c * (1.0f / 65536.0f);
            s += (double)(p * logf(p));
        }
    }
#pragma unroll
    for (int o = 32; o > 0; o >>= 1) s += __shfl_down(s, o, 64);
    if ((tid & 63) == 0) red[tid >> 6] = s;
    __syncthreads();
    if (tid == 0) {
        double t = red[0] + red[1] + red[2] + red[3];
        out[OFF_PERP] = expf((float)(-t));
        out[OFF_DIFF] = (float)(diffacc[0] * (1.0 / 16777216.0));
    }
}

extern "C" void kernel_launch(void* const* d_in, const int* in_sizes, int n_in,
                              void* d_out, int out_size, void* d_ws, size_t ws_size,
                              hipStream_t stream) {
    (void)in_sizes; (void)n_in; (void)out_size;
    const float* inp   = (const float*)d_in[0];
    const float* embed = (const float*)d_in[1];
    float* out = (float*)d_out;
    char*  ws  = (char*)d_ws;

    double*   diffacc = (double*)(ws + WS_DIFF);
    int*      counts  = (int*)(ws + WS_CNT);
    float*    enorm   = (float*)(ws + WS_EN);
    float*    enc     = (float*)(ws + WS_ENC);
    float*    embedT  = (float*)(ws + WS_ET);
    _Float16* bpk     = (_Float16*)(ws + WS_BPK);

    hipMemsetAsync(d_ws, 0, 8256, stream);   // diffacc + counts
    k_prep<<<NE / 256, 256, 0, stream>>>(embed, enorm, enc);

    if (ws_size >= WS_NEED_V2) {
        k_pack<<<256, 256, 0, stream>>>(embed, bpk, embedT);
        k_gemm<<<NROWS / 128, 256, 0, stream>>>(inp, bpk, enorm, enc, embedT,
                                                out, counts, diffacc);
    } else {
        k_main<<<NROWS / 64, 256, 0, stream>>>(inp, embed, enorm,
                                               out, counts, diffacc);
    }
    k_fin<<<1, 256, 0, stream>>>(counts, diffacc, out);
}